// Round 10
// baseline (16113.107 us; speedup 1.0000x reference)
//
#include <hip/hip_runtime.h>
#include <stdint.h>

#define T_STEPS 512
#define NB 64
#define NI 512
#define NH 1024
#define NBLK 64
#define DEPTH 16
// 64 blocks x 128 threads (2 waves); each block owns 16 h-cols = 64 gate-cols.
// Grid h-broadcast = 64 x 128 KB = 8 MB/step (half of the 128-block design).

typedef __attribute__((ext_vector_type(8))) short short8;
typedef __attribute__((ext_vector_type(4))) float floatx4;
typedef __attribute__((ext_vector_type(16))) float floatx16;
typedef __attribute__((ext_vector_type(4))) unsigned short ushortx4;
typedef __attribute__((ext_vector_type(4))) unsigned int uintx4;

__device__ __forceinline__ unsigned short f2bf(float f) {
  union { float f; uint32_t u; } v; v.f = f;
  return (unsigned short)((v.u + 0x7FFFu + ((v.u >> 16) & 1u)) >> 16);
}
__device__ __forceinline__ float bf2f(unsigned short s) {
  union { uint32_t u; float f; } v; v.u = ((uint32_t)s) << 16; return v.f;
}
__device__ __forceinline__ float sigmoid_f(float x) {
  return 1.0f / (1.0f + __expf(-x));
}
__device__ __forceinline__ float tanh_f(float x) {
  float xx = fminf(fmaxf(x, -15.0f), 15.0f);
  float e = __expf(2.0f * xx);
  return (e - 1.0f) / (e + 1.0f);
}
__device__ __forceinline__ uintx4 ntload4(const unsigned short* p) {
  return __builtin_nontemporal_load((const uintx4*)p);
}

// ---------------- prep kernels ----------------

__global__ void convert_x(const float* __restrict__ X, unsigned short* __restrict__ Xb) {
  int i = blockIdx.x * 256 + threadIdx.x;
  floatx4 x = ((const floatx4*)X)[i];
  ushortx4 o;
  o[0] = f2bf(x[0]); o[1] = f2bf(x[1]); o[2] = f2bf(x[2]); o[3] = f2bf(x[3]);
  ((ushortx4*)Xb)[i] = o;
}

// in [G][K][N] fp32 -> out [G][N][K] bf16 (n-major so K is contiguous)
__global__ void transpose_bf16(const float* __restrict__ in, unsigned short* __restrict__ outp,
                               int K, int N) {
  __shared__ float tile[64][65];
  int g = blockIdx.z;
  int k0 = blockIdx.x * 64, n0 = blockIdx.y * 64;
  int tx = threadIdx.x & 63, ty = threadIdx.x >> 6;
  const float* src = in + (size_t)g * K * N;
  unsigned short* dst = outp + (size_t)g * K * N;
#pragma unroll
  for (int i = 0; i < 16; i++) {
    int r = ty * 16 + i;
    tile[r][tx] = src[(size_t)(k0 + r) * N + n0 + tx];
  }
  __syncthreads();
#pragma unroll
  for (int i = 0; i < 16; i++) {
    int r = ty * 16 + i;
    dst[(size_t)(n0 + r) * K + k0 + tx] = f2bf(tile[tx][r]);
  }
}

__global__ void prep_small(const float* __restrict__ bi, const float* __restrict__ bh,
                           const float* __restrict__ h0, float* __restrict__ bias,
                           unsigned short* __restrict__ hbuf0, unsigned* __restrict__ flags) {
  int i = blockIdx.x * 256 + threadIdx.x;
  if (i < 4096) flags[i] = 0u;
  if (i < 4 * NH) bias[i] = bi[i] + bh[i];
  if (i < NB * NH) hbuf0[i] = f2bf(h0[i]);
}

// ---------------- Zx GEMM -> block-major Zq layout (VERBATIM R5-R7, proven) ------
// Zq element index: ((((t*4 + g)*128 + q)*2 + wm)*2 + half)*8 + jj)*16 + rr
// where b = wm*32 + row32, row32 = (rr&3) | (half<<2) | ((rr>>2)<<3), h-col = q*8 + jj.
__global__ __launch_bounds__(256) void gemm_zx(
    const unsigned short* __restrict__ Xb,
    const unsigned short* __restrict__ WibT,
    const float* __restrict__ bias,
    unsigned short* __restrict__ Zq) {
  __shared__ __align__(16) unsigned short As[128][40];  // +8 pad
  __shared__ __align__(16) unsigned short Bs[128][40];
  __shared__ __align__(16) unsigned short stg[16384];   // 32 KB stage
  const int g = blockIdx.z;
  const int m0 = blockIdx.x * 128;
  const int n0 = blockIdx.y * 128;
  const int tid = threadIdx.x;
  const int lane = tid & 63;
  const int wave = tid >> 6;
  const int wm = wave & 1, wn = wave >> 1;
  const int fr = lane & 15;
  const int fq = (lane >> 4) * 8;

  const unsigned short* Bsrc = WibT + (size_t)g * NH * NI;

  floatx4 acc[4][4];
#pragma unroll
  for (int a = 0; a < 4; a++)
#pragma unroll
    for (int b = 0; b < 4; b++)
#pragma unroll
      for (int z = 0; z < 4; z++) acc[a][b][z] = 0.0f;

  for (int k0 = 0; k0 < NI; k0 += 32) {
#pragma unroll
    for (int it = 0; it < 2; it++) {
      int c = tid + it * 256;
      int row = c >> 2, kc = (c & 3) * 8;
      *(uint4*)(&As[row][kc]) = *(const uint4*)(Xb + (size_t)(m0 + row) * NI + k0 + kc);
      *(uint4*)(&Bs[row][kc]) = *(const uint4*)(Bsrc + (size_t)(n0 + row) * NI + k0 + kc);
    }
    __syncthreads();
    short8 af[4], bf[4];
#pragma unroll
    for (int ms = 0; ms < 4; ms++) af[ms] = *(const short8*)(&As[wm * 64 + ms * 16 + fr][fq]);
#pragma unroll
    for (int ns = 0; ns < 4; ns++) bf[ns] = *(const short8*)(&Bs[wn * 64 + ns * 16 + fr][fq]);
#pragma unroll
    for (int ms = 0; ms < 4; ms++)
#pragma unroll
      for (int ns = 0; ns < 4; ns++)
        acc[ms][ns] = __builtin_amdgcn_mfma_f32_16x16x32_bf16(af[ms], bf[ns], acc[ms][ns], 0, 0, 0);
    __syncthreads();
  }

#pragma unroll
  for (int ns = 0; ns < 4; ns++) {
    int jrel = wn * 64 + ns * 16 + fr;        // col - n0, 0..127
    float bs = bias[g * NH + n0 + jrel];
    int bkp = jrel >> 3, jj = jrel & 7;
#pragma unroll
    for (int ms = 0; ms < 4; ms++) {
#pragma unroll
      for (int r = 0; r < 4; r++) {
        int mrel = wm * 64 + ms * 16 + (lane >> 4) * 4 + r;   // 0..127
        int tp = mrel >> 6, b = mrel & 63;
        int wm2 = b >> 5, row32 = b & 31;
        int half2 = (row32 >> 2) & 1;
        int rr = (row32 & 3) | ((row32 >> 3) << 2);
        int idx = (((((tp * 16 + bkp) * 2 + wm2) * 2 + half2) * 8 + jj) * 16) + rr;
        stg[idx] = f2bf(acc[ms][ns][r] + bs);
      }
    }
  }
  __syncthreads();
  const size_t t0 = (size_t)(m0 >> 6);
  const int bk0 = n0 >> 3;
#pragma unroll
  for (int tp = 0; tp < 2; tp++) {
    size_t gbase = (((t0 + tp) * 4 + g) * 128 + bk0) * 512;   // elements
#pragma unroll
    for (int c = 0; c < 4; c++) {
      int e = c * 2048 + tid * 8;
      *(uint4*)(Zq + gbase + e) = *(const uint4*)(stg + tp * 8192 + e);
    }
  }
}

// ---------------- persistent recurrent kernel ----------------
// R13 = dual-column-tile volume halving, attempt 3 — hazard class removed.
// R11/R12 NaN root cause (revised): the cross-step Zq prefetch registers were
// raw-asm "=v" outputs with the LONGEST live range in the kernel (written at
// step t end, read mid-step t+1, spanning spin + A-window). Regalloc spills
// long ranges first; spilling a register whose load is still in flight saves
// pre-arrival garbage -> NaN via zxv. Fix: Zq loads are now COMPILER-MANAGED
// (__builtin_nontemporal_load) issued at the TOP of the step that consumes
// them, BEFORE the flag spin (Zq has no flag dependence). Latency hides under
// the spin; the existing step-top vmcnt(0) drains them; no cross-step live
// range; compiler inserts correct waits if it ever spills. Counted-window
// audit: loads issued before the Prolog retire FIFO-before the A-chunks, and
// the pre-Prolog vmcnt(0) starts the window at 0 outstanding — counts are
// exactly R4's. Geometry: 64 blocks x 2 waves; one A-stream per wave feeds
// TWO 32x32 column tiles (acc0 += a*b0; acc1 += a*b1) -> grid h-broadcast
// halves to 8 MB/step (R6 measured the contended broadcast at ~1.9 TB/s;
// 16 MB/step -> 8.4 us = the floor; R8's "halving" was confounded by
// duplicated A-loads). DEPTH 16 + bs-distance 2 keep pressure ~180 VGPR.
// Sync protocol verbatim R4-R7; 64-flag single-dword poll; cached full-64B
// out lines (R8-proven).

template<int C>
__device__ __forceinline__ void load_a_c(const unsigned short* ap, short8 (&areg)[64]) {
  asm volatile("global_load_dwordx4 %0, %1, off offset:%2 sc0 sc1"
               : "=v"(areg[C]) : "v"(ap), "i"(C * 32));
}

// B frag tile T, chunk C: bfr[((T*64 + C)*64 + lane)*8] (16 B/lane, contiguous
// across the wave -> conflict-free; same layout class as R4's proven one)
template<int C, int T>
__device__ __forceinline__ void load_b_c(const unsigned short* bfr, int lane, short8 (&bs)[64]) {
  bs[C] = *(const short8*)(&bfr[((size_t)((T * 64 + C) * 64) + lane) * 8]);
}

template<int S, int I>
struct PrologR {
  static __device__ __forceinline__ void run(const unsigned short* ap, short8 (&areg)[64]) {
    load_a_c<(S + I) & 63>(ap, areg);
    PrologR<S, I + 1>::run(ap, areg);
  }
};
template<int S>
struct PrologR<S, DEPTH> {
  static __device__ __forceinline__ void run(const unsigned short*, short8 (&)[64]) {}
};

template<int S, int I>
struct ChunksR {
  static __device__ __forceinline__ void run(const unsigned short* ap, const unsigned short* bfr,
                                             int lane, short8 (&areg)[64],
                                             short8 (&bs0)[64], short8 (&bs1)[64],
                                             floatx16& acc0, floatx16& acc1) {
    if constexpr (I + DEPTH < 64) load_a_c<(S + I + DEPTH) & 63>(ap, areg);
    if constexpr (I + 2 < 64) {
      load_b_c<(S + I + 2) & 63, 0>(bfr, lane, bs0);
      load_b_c<(S + I + 2) & 63, 1>(bfr, lane, bs1);
    }
    constexpr int NOUT = (I + DEPTH < 64) ? DEPTH : (63 - I);
    constexpr int C = (S + I) & 63;
    asm volatile("s_waitcnt vmcnt(%1)" : "+v"(areg[C]) : "i"(NOUT) : "memory");
    acc0 = __builtin_amdgcn_mfma_f32_32x32x16_bf16(areg[C], bs0[C], acc0, 0, 0, 0);
    acc1 = __builtin_amdgcn_mfma_f32_32x32x16_bf16(areg[C], bs1[C], acc1, 0, 0, 0);
    ChunksR<S, I + 1>::run(ap, bfr, lane, areg, bs0, bs1, acc0, acc1);
  }
};
template<int S>
struct ChunksR<S, 64> {
  static __device__ __forceinline__ void run(const unsigned short*, const unsigned short*,
                                             int, short8 (&)[64], short8 (&)[64],
                                             short8 (&)[64], floatx16&, floatx16&) {}
};

template<int S>
__device__ __forceinline__ void lstm_step(
    int t, const unsigned short* __restrict__ Zq, unsigned short* __restrict__ hbuf,
    unsigned* __restrict__ flags, float* __restrict__ out,
    const unsigned short* bfr, const unsigned* fp,
    int tid, int lane, int wm, int nl, int g0, int jj, int half, int bk, int j0,
    size_t zoff, const int (&brow)[16], float (&creg0)[16], float (&creg1)[16]) {
  const int hsz = NB * NH;

  // ---- Zq loads for THIS step: compiler-managed nt loads, issued before the
  // spin (no flag dependence); latency hides under the spin; drained by the
  // step-top vmcnt(0). q=2bk at +0/+16B, q=2bk+1 at +1024/+1040B.
  const unsigned short* zp = Zq + (size_t)t * 262144 + zoff;
  uintx4 zq0 = ntload4(zp);
  uintx4 zq1 = ntload4(zp + 8);
  uintx4 zq2 = ntload4(zp + 512);
  uintx4 zq3 = ntload4(zp + 520);

  // ---- arrive: all 64 flags >= t (one dword per lane, agent-scope) ----
  if (t) {
    unsigned tgt = (unsigned)t;
    while (!__all((int)(__hip_atomic_load(fp, __ATOMIC_RELAXED,
                                          __HIP_MEMORY_SCOPE_AGENT) >= tgt)))
      __builtin_amdgcn_s_sleep(1);
  }
  // clean vmcnt domain for the counted A-load window (drains Zq + prior stores)
  asm volatile("s_waitcnt vmcnt(0)" ::: "memory");
  __builtin_amdgcn_sched_barrier(0);

  const unsigned short* hin = hbuf + (size_t)(t & 1) * hsz;
  unsigned short* hout = hbuf + (size_t)((t + 1) & 1) * hsz;
  const unsigned short* ap = hin + (size_t)(wm * 32 + nl) * NH + half * 8;

  floatx16 acc0, acc1;
#pragma unroll
  for (int z = 0; z < 16; z++) { acc0[z] = 0.0f; acc1[z] = 0.0f; }

  short8 areg[64];
  short8 bs0[64], bs1[64];
  PrologR<S, 0>::run(ap, areg);
  load_b_c<(S + 0) & 63, 0>(bfr, lane, bs0);
  load_b_c<(S + 0) & 63, 1>(bfr, lane, bs1);
  load_b_c<(S + 1) & 63, 0>(bfr, lane, bs0);
  load_b_c<(S + 1) & 63, 1>(bfr, lane, bs1);
  ChunksR<S, 0>::run(ap, bfr, lane, areg, bs0, bs1, acc0, acc1);
  __builtin_amdgcn_sched_barrier(0);

  unsigned zd0[8], zd1[8];
  zd0[0] = zq0[0]; zd0[1] = zq0[1]; zd0[2] = zq0[2]; zd0[3] = zq0[3];
  zd0[4] = zq1[0]; zd0[5] = zq1[1]; zd0[6] = zq1[2]; zd0[7] = zq1[3];
  zd1[0] = zq2[0]; zd1[1] = zq2[1]; zd1[2] = zq2[2]; zd1[3] = zq2[3];
  zd1[4] = zq3[0]; zd1[5] = zq3[1]; zd1[6] = zq3[2]; zd1[7] = zq3[3];

  float h0arr[16], h1arr[16];
  // epilogue tile 0 (h-cols j0..j0+7): quad exchange xor 8/16 over gate dim
#pragma unroll
  for (int r = 0; r < 16; r++) {
    unsigned dw = zd0[r >> 1];
    float zxv = bf2f((unsigned short)((r & 1) ? (dw >> 16) : (dw & 0xffffu)));
    float z0 = acc0[r] + zxv;
    float z1 = __shfl_xor(z0, 8);
    float z2 = __shfl_xor(z0, 16);
    float z3 = __shfl_xor(z1, 16);
    bool bb0 = (g0 & 1) != 0, bb1 = (g0 & 2) != 0;
    float zf = bb1 ? (bb0 ? z3 : z2) : (bb0 ? z1 : z0);
    float zi = bb1 ? (bb0 ? z2 : z3) : (bb0 ? z0 : z1);
    float zg = bb1 ? (bb0 ? z1 : z0) : (bb0 ? z3 : z2);
    float zo = bb1 ? (bb0 ? z0 : z1) : (bb0 ? z2 : z3);
    float fg = sigmoid_f(zf), ig = sigmoid_f(zi), gg = tanh_f(zg), og = sigmoid_f(zo);
    float c = fg * creg0[r] + ig * gg;
    creg0[r] = c;
    float h = og * tanh_f(c);
    h0arr[r] = h;
    if (g0 == 0)
      __hip_atomic_store(&hout[(size_t)brow[r] * NH + j0 + jj], f2bf(h),
                         __ATOMIC_RELAXED, __HIP_MEMORY_SCOPE_AGENT);
  }
  // epilogue tile 1 (h-cols j0+8..j0+15)
#pragma unroll
  for (int r = 0; r < 16; r++) {
    unsigned dw = zd1[r >> 1];
    float zxv = bf2f((unsigned short)((r & 1) ? (dw >> 16) : (dw & 0xffffu)));
    float z0 = acc1[r] + zxv;
    float z1 = __shfl_xor(z0, 8);
    float z2 = __shfl_xor(z0, 16);
    float z3 = __shfl_xor(z1, 16);
    bool bb0 = (g0 & 1) != 0, bb1 = (g0 & 2) != 0;
    float zf = bb1 ? (bb0 ? z3 : z2) : (bb0 ? z1 : z0);
    float zi = bb1 ? (bb0 ? z2 : z3) : (bb0 ? z0 : z1);
    float zg = bb1 ? (bb0 ? z1 : z0) : (bb0 ? z3 : z2);
    float zo = bb1 ? (bb0 ? z0 : z1) : (bb0 ? z2 : z3);
    float fg = sigmoid_f(zf), ig = sigmoid_f(zi), gg = tanh_f(zg), og = sigmoid_f(zo);
    float c = fg * creg1[r] + ig * gg;
    creg1[r] = c;
    float h = og * tanh_f(c);
    h1arr[r] = h;
    if (g0 == 0)
      __hip_atomic_store(&hout[(size_t)brow[r] * NH + j0 + 8 + jj], f2bf(h),
                         __ATOMIC_RELAXED, __HIP_MEMORY_SCOPE_AGENT);
  }

  if (t + 1 < T_STEPS) {
    // ---- release: h stores at coherence point, then post flag ----
    asm volatile("s_waitcnt vmcnt(0)" ::: "memory");
    __syncthreads();                                   // both waves drained
    if (tid == 0)
      __hip_atomic_store(flags + bk, (unsigned)(t + 1),
                         __ATOMIC_RELAXED, __HIP_MEMORY_SCOPE_AGENT);
  }

  // out stores: block owns 16 consecutive fp32 cols = full 64B lines -> cached
  if (g0 == 0) {
#pragma unroll
    for (int r = 0; r < 16; r++) {
      size_t obase = (size_t)t * hsz + (size_t)brow[r] * NH + j0;
      out[obase + jj] = h0arr[r];
      out[obase + 8 + jj] = h1arr[r];
      if (t == T_STEPS - 1) {
        size_t nbase = (size_t)T_STEPS * hsz + (size_t)brow[r] * NH + j0;  // h_n
        out[nbase + jj] = h0arr[r];
        out[nbase + 8 + jj] = h1arr[r];
      }
    }
  }
}

template<int S>
__device__ __forceinline__ void lstm_loop(
    const unsigned short* __restrict__ Zq, unsigned short* __restrict__ hbuf,
    unsigned* __restrict__ flags, float* __restrict__ out,
    const unsigned short* bfr, const unsigned* fp,
    int tid, int lane, int wm, int nl, int g0, int jj, int half, int bk, int j0,
    size_t zoff, const int (&brow)[16], float (&creg0)[16], float (&creg1)[16]) {
  for (int t = 0; t < T_STEPS; t++) {
    lstm_step<S>(t, Zq, hbuf, flags, out, bfr, fp, tid, lane, wm, nl, g0, jj,
                 half, bk, j0, zoff, brow, creg0, creg1);
  }
}

__global__ __launch_bounds__(128, 1) void lstm_persist(
    const unsigned short* __restrict__ Zq,
    const unsigned short* __restrict__ WhT,   // [4][NH(n)][NH(k)] bf16
    const float* __restrict__ c0,
    unsigned short* __restrict__ hbuf,        // 2 x NB x NH bf16
    unsigned* __restrict__ flags,             // 64 dwords used
    float* __restrict__ out) {
  // 2 tiles x [kk(64)][lane(64)][8 shorts] = 128 KB
  __shared__ __align__(16) unsigned short bfr[2 * 64 * 64 * 8];

  const int bk = blockIdx.x;       // 0..63
  const int j0 = bk * 16;
  const int tid = threadIdx.x;
  const int lane = tid & 63;
  const int wm = tid >> 6;        // wave = batch half (m-tile of 32)
  const int nl = lane & 31;       // MFMA col n: gate g0 = n>>3, h-col jj = n&7
  const int g0 = nl >> 3;
  const int jj = nl & 7;
  const int half = lane >> 5;

  // Fill B fragments, tile c: B[k][n] = Wh[g][k][j0+c*8+jj] = WhT[g][j0+c*8+jj][k]
  for (int i = 0; i < 64; i++) {
    int f = tid + i * 128;        // 0..8191 = c*4096 + kk*64 + fl
    int c = f >> 12, rem = f & 4095;
    int kk = rem >> 6, fl = rem & 63;
    int n = fl & 31;
    size_t wrow = (size_t)(n >> 3) * NH + j0 + c * 8 + (n & 7);
    int kb = kk * 16 + (fl >> 5) * 8;
    uint4 v = *(const uint4*)(WhT + wrow * NH + kb);
    *(uint4*)(&bfr[(size_t)f * 8]) = v;
  }

  // c state in C/D layout: row = (r&3) + 8*(r>>2) + 4*half
  float creg0[16], creg1[16];
  int brow[16];
#pragma unroll
  for (int r = 0; r < 16; r++) {
    brow[r] = wm * 32 + (r & 3) + 8 * (r >> 2) + 4 * half;
    creg0[r] = c0[(size_t)brow[r] * NH + j0 + jj];
    creg1[r] = c0[(size_t)brow[r] * NH + j0 + 8 + jj];
  }
  __syncthreads();

  const unsigned* fp = flags + lane;   // lane polls flag[lane] (64 flags)
  // R5-R7 Zq layout, q = 2*bk (tile 0); tile 1 = q+1 at +512 elements
  const size_t zoff =
      (((((size_t)g0 * 128 + 2 * bk) * 2 + wm) * 2 + half) * 8 + jj) * 16;

  switch (bk & 3) {
    case 0: lstm_loop<0>(Zq, hbuf, flags, out, bfr, fp, tid, lane, wm, nl, g0, jj,
                         half, bk, j0, zoff, brow, creg0, creg1); break;
    case 1: lstm_loop<16>(Zq, hbuf, flags, out, bfr, fp, tid, lane, wm, nl, g0, jj,
                          half, bk, j0, zoff, brow, creg0, creg1); break;
    case 2: lstm_loop<32>(Zq, hbuf, flags, out, bfr, fp, tid, lane, wm, nl, g0, jj,
                          half, bk, j0, zoff, brow, creg0, creg1); break;
    default: lstm_loop<48>(Zq, hbuf, flags, out, bfr, fp, tid, lane, wm, nl, g0, jj,
                           half, bk, j0, zoff, brow, creg0, creg1); break;
  }

  // c_n (full 64B lines, cached)
  if (g0 == 0) {
#pragma unroll
    for (int r = 0; r < 16; r++) {
      size_t nbase = (size_t)T_STEPS * NB * NH + NB * NH + (size_t)brow[r] * NH + j0;
      out[nbase + jj] = creg0[r];
      out[nbase + 8 + jj] = creg1[r];
    }
  }
}

// ---------------- host launcher ----------------
extern "C" void kernel_launch(void* const* d_in, const int* in_sizes, int n_in,
                              void* d_out, int out_size, void* d_ws, size_t ws_size,
                              hipStream_t stream) {
  const float* X  = (const float*)d_in[0];
  const float* h0 = (const float*)d_in[1];
  const float* c0 = (const float*)d_in[2];
  const float* Wi = (const float*)d_in[3];
  const float* Wh = (const float*)d_in[4];
  const float* bi = (const float*)d_in[5];
  const float* bh = (const float*)d_in[6];
  float* out = (float*)d_out;

  uint8_t* ws = (uint8_t*)d_ws;
  size_t off = 0;
  auto alloc = [&](size_t bytes) -> void* {
    void* p = ws + off;
    off += (bytes + 255) & ~(size_t)255;
    return p;
  };
  unsigned short* Zq   = (unsigned short*)alloc((size_t)T_STEPS * NB * 4096 * 2);  // 268 MB
  unsigned short* Xb   = (unsigned short*)alloc((size_t)T_STEPS * NB * NI * 2);    // 33.6 MB
  unsigned short* WibT = (unsigned short*)alloc((size_t)4 * NH * NI * 2);          // 4.2 MB
  unsigned short* WhT  = (unsigned short*)alloc((size_t)4 * NH * NH * 2);          // 8.4 MB
  float* bias          = (float*)alloc((size_t)4 * NH * 4);
  unsigned short* hbuf = (unsigned short*)alloc((size_t)2 * NB * NH * 2);          // 256 KB
  unsigned* flags      = (unsigned*)alloc((size_t)4096 * 4);                       // 16 KB

  if (off > ws_size) {
    hipMemsetAsync(d_out, 0x7F, (size_t)out_size * 4, stream);
    return;
  }

  convert_x<<<16384, 256, 0, stream>>>(X, Xb);
  transpose_bf16<<<dim3(8, 16, 4), 256, 0, stream>>>(Wi, WibT, NI, NH);
  transpose_bf16<<<dim3(16, 16, 4), 256, 0, stream>>>(Wh, WhT, NH, NH);
  prep_small<<<256, 256, 0, stream>>>(bi, bh, h0, bias, hbuf, flags);
  gemm_zx<<<dim3(256, 8, 4), 256, 0, stream>>>(Xb, WibT, bias, Zq);

  lstm_persist<<<dim3(NBLK), dim3(128), 0, stream>>>(Zq, WhT, c0, hbuf, flags, out);
}